// Round 1
// baseline (5621.753 us; speedup 1.0000x reference)
//
#include <hip/hip_runtime.h>

#define NN 20000
#define NE 640000
#define CIN 256
#define CHID 256
#define COUT 128
#define NR 8

// ---- count edges per (dst, relation) ----
__global__ void count_kernel(const int* __restrict__ dst, const int* __restrict__ et,
                             int* __restrict__ cnt) {
    int e = blockIdx.x * blockDim.x + threadIdx.x;
    if (e < NE) atomicAdd(&cnt[dst[e] * NR + et[e]], 1);
}

// ---- scatter x[src]*norm into A[dst] for edges of relation r ----
// one wave per edge; 64 lanes x float4 = 256 channels
__global__ void scatter_kernel(const float* __restrict__ xin,
                               const int* __restrict__ src,
                               const int* __restrict__ dst,
                               const int* __restrict__ et,
                               const int* __restrict__ cnt,
                               float* __restrict__ A, int r) {
    int gid  = blockIdx.x * blockDim.x + threadIdx.x;
    int wid  = gid >> 6;
    int lane = threadIdx.x & 63;
    int nw   = (gridDim.x * blockDim.x) >> 6;
    for (int e = wid; e < NE; e += nw) {
        if (et[e] != r) continue;               // wave-uniform branch
        int s = src[e], d = dst[e];
        float norm = 1.0f / (float)max(cnt[d * NR + r], 1);
        float4 v = *reinterpret_cast<const float4*>(xin + (size_t)s * 256 + lane * 4);
        float* o = A + (size_t)d * 256 + lane * 4;
        unsafeAtomicAdd(o + 0, v.x * norm);
        unsafeAtomicAdd(o + 1, v.y * norm);
        unsafeAtomicAdd(o + 2, v.z * norm);
        unsafeAtomicAdd(o + 3, v.w * norm);
    }
}

// ---- C[M x Nc] += A[M x K] @ B[K x Nc], row-major, tiled 64x64, 256 thr ----
__global__ __launch_bounds__(256) void gemm_acc(const float* __restrict__ Am,
                                                const float* __restrict__ Bm,
                                                float* __restrict__ Cm,
                                                int M, int K, int Nc) {
    __shared__ float As[16][65];   // [k][m]
    __shared__ float Bs[16][65];   // [k][n]
    const int tid = threadIdx.x;
    const int tx = tid & 15, ty = tid >> 4;
    const int row0 = blockIdx.x * 64;
    const int col0 = blockIdx.y * 64;
    float acc[4][4] = {};
    for (int k0 = 0; k0 < K; k0 += 16) {
        {   // A tile: 64 rows x 16 k
            int m  = tid >> 2;
            int kk = (tid & 3) * 4;
            float4 v = make_float4(0.f, 0.f, 0.f, 0.f);
            if (row0 + m < M)
                v = *reinterpret_cast<const float4*>(Am + (size_t)(row0 + m) * K + k0 + kk);
            As[kk + 0][m] = v.x; As[kk + 1][m] = v.y;
            As[kk + 2][m] = v.z; As[kk + 3][m] = v.w;
        }
        {   // B tile: 16 k x 64 n
            int kk = tid >> 4;
            int n  = (tid & 15) * 4;
            float4 v = *reinterpret_cast<const float4*>(Bm + (size_t)(k0 + kk) * Nc + col0 + n);
            Bs[kk][n + 0] = v.x; Bs[kk][n + 1] = v.y;
            Bs[kk][n + 2] = v.z; Bs[kk][n + 3] = v.w;
        }
        __syncthreads();
        #pragma unroll
        for (int kk = 0; kk < 16; ++kk) {
            float a0 = As[kk][ty * 4 + 0], a1 = As[kk][ty * 4 + 1];
            float a2 = As[kk][ty * 4 + 2], a3 = As[kk][ty * 4 + 3];
            float b0 = Bs[kk][tx * 4 + 0], b1 = Bs[kk][tx * 4 + 1];
            float b2 = Bs[kk][tx * 4 + 2], b3 = Bs[kk][tx * 4 + 3];
            acc[0][0] += a0 * b0; acc[0][1] += a0 * b1; acc[0][2] += a0 * b2; acc[0][3] += a0 * b3;
            acc[1][0] += a1 * b0; acc[1][1] += a1 * b1; acc[1][2] += a1 * b2; acc[1][3] += a1 * b3;
            acc[2][0] += a2 * b0; acc[2][1] += a2 * b1; acc[2][2] += a2 * b2; acc[2][3] += a2 * b3;
            acc[3][0] += a3 * b0; acc[3][1] += a3 * b1; acc[3][2] += a3 * b2; acc[3][3] += a3 * b3;
        }
        __syncthreads();
    }
    #pragma unroll
    for (int i = 0; i < 4; ++i) {
        int m = row0 + ty * 4 + i;
        if (m < M) {
            float* cp = Cm + (size_t)m * Nc + col0 + tx * 4;
            cp[0] += acc[i][0]; cp[1] += acc[i][1];
            cp[2] += acc[i][2]; cp[3] += acc[i][3];
        }
    }
}

__global__ void init_bias(float* __restrict__ out, const float* __restrict__ b,
                          int total, int Nc) {
    int i = blockIdx.x * blockDim.x + threadIdx.x;
    if (i < total) out[i] = b[i & (Nc - 1)];   // Nc is a power of two
}

__global__ void relu_kernel(float* __restrict__ h, int n4) {
    int i = blockIdx.x * blockDim.x + threadIdx.x;
    if (i < n4) {
        float4* p = reinterpret_cast<float4*>(h) + i;
        float4 v = *p;
        v.x = fmaxf(v.x, 0.f); v.y = fmaxf(v.y, 0.f);
        v.z = fmaxf(v.z, 0.f); v.w = fmaxf(v.w, 0.f);
        *p = v;
    }
}

extern "C" void kernel_launch(void* const* d_in, const int* in_sizes, int n_in,
                              void* d_out, int out_size, void* d_ws, size_t ws_size,
                              hipStream_t stream) {
    const float* x     = (const float*)d_in[0];
    const float* W1    = (const float*)d_in[1];
    const float* root1 = (const float*)d_in[2];
    const float* b1    = (const float*)d_in[3];
    const float* W2    = (const float*)d_in[4];
    const float* root2 = (const float*)d_in[5];
    const float* b2    = (const float*)d_in[6];
    const int*   ei    = (const int*)d_in[7];
    const int*   et    = (const int*)d_in[8];
    const int* src = ei;          // edge_index row 0
    const int* dst = ei + NE;     // edge_index row 1
    float* out = (float*)d_out;

    char* ws = (char*)d_ws;
    int*   cnt = (int*)ws;                                      // 640 KB
    float* A   = (float*)(ws + (1 << 20));                      // 20.5 MB
    float* h   = (float*)(ws + (1 << 20) + (size_t)NN * 256 * 4); // 20.5 MB

    // counts (shared by both layers)
    hipMemsetAsync(cnt, 0, (size_t)NN * NR * 4, stream);
    count_kernel<<<(NE + 255) / 256, 256, 0, stream>>>(dst, et, cnt);

    // ---- layer 1: h = relu(sum_r mean_r(x) @ W1[r] + x @ root1 + b1) ----
    init_bias<<<(NN * CHID + 255) / 256, 256, 0, stream>>>(h, b1, NN * CHID, CHID);
    dim3 g1((NN + 63) / 64, CHID / 64);
    gemm_acc<<<g1, 256, 0, stream>>>(x, root1, h, NN, CIN, CHID);
    for (int r = 0; r < NR; ++r) {
        hipMemsetAsync(A, 0, (size_t)NN * 256 * 4, stream);
        scatter_kernel<<<20000, 256, 0, stream>>>(x, src, dst, et, cnt, A, r);
        gemm_acc<<<g1, 256, 0, stream>>>(A, W1 + (size_t)r * CIN * CHID, h, NN, CIN, CHID);
    }
    relu_kernel<<<(NN * CHID / 4 + 255) / 256, 256, 0, stream>>>(h, NN * CHID / 4);

    // ---- layer 2: out = sum_r mean_r(h) @ W2[r] + h @ root2 + b2 ----
    init_bias<<<(NN * COUT + 255) / 256, 256, 0, stream>>>(out, b2, NN * COUT, COUT);
    dim3 g2((NN + 63) / 64, COUT / 64);
    gemm_acc<<<g2, 256, 0, stream>>>(h, root2, out, NN, CHID, COUT);
    for (int r = 0; r < NR; ++r) {
        hipMemsetAsync(A, 0, (size_t)NN * 256 * 4, stream);
        scatter_kernel<<<20000, 256, 0, stream>>>(h, src, dst, et, cnt, A, r);
        gemm_acc<<<g2, 256, 0, stream>>>(A, W2 + (size_t)r * CHID * COUT, out, NN, CHID, COUT);
    }
}

// Round 2
// 1442.033 us; speedup vs baseline: 3.8985x; 3.8985x over previous
//
#include <hip/hip_runtime.h>

#define NN 20000
#define NE 640000
#define CIN 256
#define CHID 256
#define COUT 128
#define NR 8
#define NSEG (NN * NR)   // 160000 (rel-major: idx = r*NN + n)

// ---- count edges per (rel, dst) ----
__global__ void count_kernel(const int* __restrict__ dst, const int* __restrict__ et,
                             int* __restrict__ cnt) {
    int e = blockIdx.x * blockDim.x + threadIdx.x;
    if (e < NE) atomicAdd(&cnt[et[e] * NN + dst[e]], 1);
}

// ---- 3-kernel exclusive scan over NSEG entries ----
__global__ void scan1(const int* __restrict__ cnt, int* __restrict__ off,
                      int* __restrict__ bsum) {
    __shared__ int s[256];
    int i = blockIdx.x * 256 + threadIdx.x;
    int v = (i < NSEG) ? cnt[i] : 0;
    s[threadIdx.x] = v;
    __syncthreads();
    for (int d = 1; d < 256; d <<= 1) {
        int t = (threadIdx.x >= d) ? s[threadIdx.x - d] : 0;
        __syncthreads();
        s[threadIdx.x] += t;
        __syncthreads();
    }
    if (i < NSEG) off[i] = s[threadIdx.x] - v;     // exclusive
    if (threadIdx.x == 255) bsum[blockIdx.x] = s[255];
}

__global__ void scan2(int* __restrict__ bsum, int nb) {
    if (blockIdx.x == 0 && threadIdx.x == 0) {
        int acc = 0;
        for (int b = 0; b < nb; ++b) { int t = bsum[b]; bsum[b] = acc; acc += t; }
    }
}

__global__ void scan3(int* __restrict__ off, const int* __restrict__ bsum,
                      int* __restrict__ cursor) {
    int i = blockIdx.x * 256 + threadIdx.x;
    if (i < NSEG) {
        int o = off[i] + bsum[blockIdx.x];
        off[i] = o;
        cursor[i] = o;
    }
}

// ---- bucket edges by (rel, dst); store src ----
__global__ void bucket_kernel(const int* __restrict__ src, const int* __restrict__ dst,
                              const int* __restrict__ et, int* __restrict__ cursor,
                              int* __restrict__ ss) {
    int e = blockIdx.x * blockDim.x + threadIdx.x;
    if (e < NE) {
        int p = atomicAdd(&cursor[et[e] * NN + dst[e]], 1);
        ss[p] = src[e];
    }
}

// ---- gather: one wave per dst node; A[n] = mean of x[src] over segment ----
__global__ __launch_bounds__(256) void gather_kernel(const float* __restrict__ xin,
                                                     const int* __restrict__ ss,
                                                     const int* __restrict__ off,
                                                     const int* __restrict__ cnt,
                                                     float* __restrict__ A, int r) {
    int n    = (blockIdx.x * 256 + threadIdx.x) >> 6;
    int lane = threadIdx.x & 63;
    if (n >= NN) return;
    int idx  = r * NN + n;
    int base = off[idx];
    int c    = cnt[idx];
    float4 acc = make_float4(0.f, 0.f, 0.f, 0.f);
    for (int j = 0; j < c; ++j) {
        int s = ss[base + j];
        float4 v = *reinterpret_cast<const float4*>(xin + (size_t)s * 256 + lane * 4);
        acc.x += v.x; acc.y += v.y; acc.z += v.z; acc.w += v.w;
    }
    float inv = (c > 0) ? 1.0f / (float)c : 0.f;
    acc.x *= inv; acc.y *= inv; acc.z *= inv; acc.w *= inv;
    *reinterpret_cast<float4*>(A + (size_t)n * 256 + lane * 4) = acc;
}

// ---- C[M x Nc] += A[M x K] @ B[K x Nc], row-major, tiled 64x64, 256 thr ----
__global__ __launch_bounds__(256) void gemm_acc(const float* __restrict__ Am,
                                                const float* __restrict__ Bm,
                                                float* __restrict__ Cm,
                                                int M, int K, int Nc) {
    __shared__ float As[16][65];
    __shared__ float Bs[16][65];
    const int tid = threadIdx.x;
    const int tx = tid & 15, ty = tid >> 4;
    const int row0 = blockIdx.x * 64;
    const int col0 = blockIdx.y * 64;
    float acc[4][4] = {};
    for (int k0 = 0; k0 < K; k0 += 16) {
        {
            int m  = tid >> 2;
            int kk = (tid & 3) * 4;
            float4 v = make_float4(0.f, 0.f, 0.f, 0.f);
            if (row0 + m < M)
                v = *reinterpret_cast<const float4*>(Am + (size_t)(row0 + m) * K + k0 + kk);
            As[kk + 0][m] = v.x; As[kk + 1][m] = v.y;
            As[kk + 2][m] = v.z; As[kk + 3][m] = v.w;
        }
        {
            int kk = tid >> 4;
            int n  = (tid & 15) * 4;
            float4 v = *reinterpret_cast<const float4*>(Bm + (size_t)(k0 + kk) * Nc + col0 + n);
            Bs[kk][n + 0] = v.x; Bs[kk][n + 1] = v.y;
            Bs[kk][n + 2] = v.z; Bs[kk][n + 3] = v.w;
        }
        __syncthreads();
        #pragma unroll
        for (int kk = 0; kk < 16; ++kk) {
            float a0 = As[kk][ty * 4 + 0], a1 = As[kk][ty * 4 + 1];
            float a2 = As[kk][ty * 4 + 2], a3 = As[kk][ty * 4 + 3];
            float b0 = Bs[kk][tx * 4 + 0], b1 = Bs[kk][tx * 4 + 1];
            float b2 = Bs[kk][tx * 4 + 2], b3 = Bs[kk][tx * 4 + 3];
            acc[0][0] += a0 * b0; acc[0][1] += a0 * b1; acc[0][2] += a0 * b2; acc[0][3] += a0 * b3;
            acc[1][0] += a1 * b0; acc[1][1] += a1 * b1; acc[1][2] += a1 * b2; acc[1][3] += a1 * b3;
            acc[2][0] += a2 * b0; acc[2][1] += a2 * b1; acc[2][2] += a2 * b2; acc[2][3] += a2 * b3;
            acc[3][0] += a3 * b0; acc[3][1] += a3 * b1; acc[3][2] += a3 * b2; acc[3][3] += a3 * b3;
        }
        __syncthreads();
    }
    #pragma unroll
    for (int i = 0; i < 4; ++i) {
        int m = row0 + ty * 4 + i;
        if (m < M) {
            float* cp = Cm + (size_t)m * Nc + col0 + tx * 4;
            cp[0] += acc[i][0]; cp[1] += acc[i][1];
            cp[2] += acc[i][2]; cp[3] += acc[i][3];
        }
    }
}

__global__ void init_bias(float* __restrict__ out, const float* __restrict__ b,
                          int total, int Nc) {
    int i = blockIdx.x * blockDim.x + threadIdx.x;
    if (i < total) out[i] = b[i & (Nc - 1)];
}

__global__ void relu_kernel(float* __restrict__ h, int n4) {
    int i = blockIdx.x * blockDim.x + threadIdx.x;
    if (i < n4) {
        float4* p = reinterpret_cast<float4*>(h) + i;
        float4 v = *p;
        v.x = fmaxf(v.x, 0.f); v.y = fmaxf(v.y, 0.f);
        v.z = fmaxf(v.z, 0.f); v.w = fmaxf(v.w, 0.f);
        *p = v;
    }
}

extern "C" void kernel_launch(void* const* d_in, const int* in_sizes, int n_in,
                              void* d_out, int out_size, void* d_ws, size_t ws_size,
                              hipStream_t stream) {
    const float* x     = (const float*)d_in[0];
    const float* W1    = (const float*)d_in[1];
    const float* root1 = (const float*)d_in[2];
    const float* b1    = (const float*)d_in[3];
    const float* W2    = (const float*)d_in[4];
    const float* root2 = (const float*)d_in[5];
    const float* b2    = (const float*)d_in[6];
    const int*   ei    = (const int*)d_in[7];
    const int*   et    = (const int*)d_in[8];
    const int* src = ei;
    const int* dst = ei + NE;
    float* out = (float*)d_out;

    char* ws = (char*)d_ws;
    int*   cnt    = (int*)(ws + 0);            // 640 KB
    int*   off    = (int*)(ws + 640000);       // 640 KB
    int*   cursor = (int*)(ws + 1280000);      // 640 KB
    int*   bsum   = (int*)(ws + 1920000);      // 4 KB (625 ints)
    int*   ss     = (int*)(ws + 1924096);      // 2.56 MB
    float* A      = (float*)(ws + 4484096);    // 20.48 MB
    float* h      = (float*)(ws + 24964096);   // 20.48 MB  (end ~45.4 MB)

    const int NB = (NSEG + 255) / 256;         // 625

    // ---- build CSR by (rel, dst) ----
    hipMemsetAsync(cnt, 0, (size_t)NSEG * 4, stream);
    count_kernel<<<(NE + 255) / 256, 256, 0, stream>>>(dst, et, cnt);
    scan1<<<NB, 256, 0, stream>>>(cnt, off, bsum);
    scan2<<<1, 64, 0, stream>>>(bsum, NB);
    scan3<<<NB, 256, 0, stream>>>(off, bsum, cursor);
    bucket_kernel<<<(NE + 255) / 256, 256, 0, stream>>>(src, dst, et, cursor, ss);

    // ---- layer 1: h = relu(sum_r mean_r(x) @ W1[r] + x @ root1 + b1) ----
    init_bias<<<(NN * CHID + 255) / 256, 256, 0, stream>>>(h, b1, NN * CHID, CHID);
    dim3 g1((NN + 63) / 64, CHID / 64);
    gemm_acc<<<g1, 256, 0, stream>>>(x, root1, h, NN, CIN, CHID);
    for (int r = 0; r < NR; ++r) {
        gather_kernel<<<(NN * 64 + 255) / 256, 256, 0, stream>>>(x, ss, off, cnt, A, r);
        gemm_acc<<<g1, 256, 0, stream>>>(A, W1 + (size_t)r * CIN * CHID, h, NN, CIN, CHID);
    }
    relu_kernel<<<(NN * CHID / 4 + 255) / 256, 256, 0, stream>>>(h, NN * CHID / 4);

    // ---- layer 2: out = sum_r mean_r(h) @ W2[r] + h @ root2 + b2 ----
    init_bias<<<(NN * COUT + 255) / 256, 256, 0, stream>>>(out, b2, NN * COUT, COUT);
    dim3 g2((NN + 63) / 64, COUT / 64);
    gemm_acc<<<g2, 256, 0, stream>>>(h, root2, out, NN, CHID, COUT);
    for (int r = 0; r < NR; ++r) {
        gather_kernel<<<(NN * 64 + 255) / 256, 256, 0, stream>>>(h, ss, off, cnt, A, r);
        gemm_acc<<<g2, 256, 0, stream>>>(A, W2 + (size_t)r * CHID * COUT, out, NN, CHID, COUT);
    }
}

// Round 4
// 630.357 us; speedup vs baseline: 8.9184x; 2.2876x over previous
//
#include <hip/hip_runtime.h>

#define NN 20000
#define NE 640000
#define NR 8
#define NSEG (NN * NR)
#define KCAT 2304            // 256 (root/self) + 8*256 (relations)
#define CH1 256
#define CH2 128

typedef __attribute__((ext_vector_type(8))) short short8;
typedef __attribute__((ext_vector_type(4))) float f32x4;

__device__ __forceinline__ float bf2f(unsigned short u) {
    unsigned int x = ((unsigned int)u) << 16;
    return __builtin_bit_cast(float, x);
}
__device__ __forceinline__ unsigned short f2bf(float f) {
    unsigned int u = __builtin_bit_cast(unsigned int, f);
    u = (u + 0x7FFFu + ((u >> 16) & 1u)) >> 16;   // RNE
    return (unsigned short)u;
}

// ================= CSR build =================
__global__ void count_kernel(const int* __restrict__ dst, const int* __restrict__ et,
                             int* __restrict__ cnt) {
    int e = blockIdx.x * blockDim.x + threadIdx.x;
    if (e < NE) atomicAdd(&cnt[et[e] * NN + dst[e]], 1);
}

__global__ void scan1(const int* __restrict__ cnt, int* __restrict__ off,
                      int* __restrict__ bsum) {
    __shared__ int s[256];
    int i = blockIdx.x * 256 + threadIdx.x;
    int v = (i < NSEG) ? cnt[i] : 0;
    s[threadIdx.x] = v;
    __syncthreads();
    for (int d = 1; d < 256; d <<= 1) {
        int t = (threadIdx.x >= d) ? s[threadIdx.x - d] : 0;
        __syncthreads();
        s[threadIdx.x] += t;
        __syncthreads();
    }
    if (i < NSEG) off[i] = s[threadIdx.x] - v;
    if (threadIdx.x == 255) bsum[blockIdx.x] = s[255];
}

__global__ void scan2(int* __restrict__ bsum, int nb) {
    if (blockIdx.x == 0 && threadIdx.x == 0) {
        int acc = 0;
        for (int b = 0; b < nb; ++b) { int t = bsum[b]; bsum[b] = acc; acc += t; }
    }
}

__global__ void scan3(int* __restrict__ off, const int* __restrict__ bsum,
                      int* __restrict__ cursor) {
    int i = blockIdx.x * 256 + threadIdx.x;
    if (i < NSEG) {
        int o = off[i] + bsum[blockIdx.x];
        off[i] = o;
        cursor[i] = o;
    }
}

__global__ void bucket_kernel(const int* __restrict__ src, const int* __restrict__ dst,
                              const int* __restrict__ et, int* __restrict__ cursor,
                              int* __restrict__ ss) {
    int e = blockIdx.x * blockDim.x + threadIdx.x;
    if (e < NE) {
        int p = atomicAdd(&cursor[et[e] * NN + dst[e]], 1);
        ss[p] = src[e];
    }
}

// ================= conversions / packing =================
__global__ void cvt_bf16(const float* __restrict__ in, unsigned short* __restrict__ ob, int n4) {
    int i = blockIdx.x * blockDim.x + threadIdx.x;
    if (i < n4) {
        float4 v = reinterpret_cast<const float4*>(in)[i];
        ushort4 o;
        o.x = f2bf(v.x); o.y = f2bf(v.y); o.z = f2bf(v.z); o.w = f2bf(v.w);
        reinterpret_cast<ushort4*>(ob)[i] = o;
    }
}

// WT[n][k] over k<KCAT: k<256 -> root[k][n]; else W[r][kk][n]
__global__ void build_wt(const float* __restrict__ root, const float* __restrict__ W,
                         unsigned short* __restrict__ WT, int nout) {
    int i = blockIdx.x * 256 + threadIdx.x;
    if (i >= nout * KCAT) return;
    int n = i / KCAT, k = i - n * KCAT;
    float v;
    if (k < 256) v = root[(size_t)k * nout + n];
    else { int r = (k - 256) >> 8, kk = (k - 256) & 255; v = W[((size_t)r * 256 + kk) * nout + n]; }
    WT[(size_t)n * KCAT + k] = f2bf(v);
}

// copy bf16 rows [n0, n0+rows) of src (ld 256) into A chunk cols 0..255 (ld KCAT)
__global__ void copy_rows(const unsigned short* __restrict__ src, unsigned short* __restrict__ A,
                          int n0, int rows) {
    int t = blockIdx.x * 256 + threadIdx.x;
    int row = t >> 6, c = t & 63;
    if (row < rows)
        reinterpret_cast<ushort4*>(A + (size_t)row * KCAT)[c] =
            reinterpret_cast<const ushort4*>(src + (size_t)(n0 + row) * 256)[c];
}

// one wave per (relation, node) segment: mean of bf16 rows -> A cols 256+r*256
__global__ __launch_bounds__(256) void gather_all(const unsigned short* __restrict__ xb,
                                                  const int* __restrict__ ss,
                                                  const int* __restrict__ off,
                                                  const int* __restrict__ cnt,
                                                  unsigned short* __restrict__ A,
                                                  int n0, int rows) {
    int wid  = blockIdx.x * 4 + (threadIdx.x >> 6);
    int lane = threadIdx.x & 63;
    if (wid >= rows * NR) return;
    int r = wid / rows;
    int n = n0 + (wid - r * rows);
    int idx  = r * NN + n;
    int base = off[idx];
    int c    = cnt[idx];
    float a0 = 0.f, a1 = 0.f, a2 = 0.f, a3 = 0.f;
    for (int j = 0; j < c; ++j) {
        int s = ss[base + j];
        ushort4 v = reinterpret_cast<const ushort4*>(xb + (size_t)s * 256)[lane];
        a0 += bf2f(v.x); a1 += bf2f(v.y); a2 += bf2f(v.z); a3 += bf2f(v.w);
    }
    float inv = (c > 0) ? 1.f / (float)c : 0.f;
    ushort4 o;
    o.x = f2bf(a0 * inv); o.y = f2bf(a1 * inv); o.z = f2bf(a2 * inv); o.w = f2bf(a3 * inv);
    reinterpret_cast<ushort4*>(A + (size_t)(wid - r * rows) * KCAT + 256 + r * 256)[lane] = o;
}

// ================= MFMA GEMM =================
// C[M x NOUT] = A[M x KCAT](bf16) @ BT[NOUT x KCAT]^T(bf16) + bias; epilogue per template.
template<int NOUT, bool RELU_BF16>
__global__ __launch_bounds__(256) void gemm_mfma(const unsigned short* __restrict__ A,
                                                 const unsigned short* __restrict__ BT,
                                                 const float* __restrict__ bias,
                                                 void* __restrict__ Cout,
                                                 int M, int mrow0) {
    __shared__ __align__(16) short As[128 * 40];   // pad: 40-short row stride
    __shared__ __align__(16) short Bs[128 * 40];
    const int tid  = threadIdx.x;
    const int lane = tid & 63;
    const int w    = tid >> 6;
    const int wr   = w >> 1, wc = w & 1;
    const int row0 = blockIdx.x * 128;
    const int col0 = blockIdx.y * 128;

    f32x4 acc[4][4] = {};

    const int srow = tid >> 2;          // 0..63
    const int sc   = (tid & 3) * 8;     // k offset: 0,8,16,24

    for (int k0 = 0; k0 < KCAT; k0 += 32) {
        int r1 = srow, r2 = srow + 64;
        short8 va = {}, vb = {};
        if (row0 + r1 < M) va = *reinterpret_cast<const short8*>(A + (size_t)(row0 + r1) * KCAT + k0 + sc);
        if (row0 + r2 < M) vb = *reinterpret_cast<const short8*>(A + (size_t)(row0 + r2) * KCAT + k0 + sc);
        *reinterpret_cast<short8*>(&As[r1 * 40 + sc]) = va;
        *reinterpret_cast<short8*>(&As[r2 * 40 + sc]) = vb;
        short8 wa = *reinterpret_cast<const short8*>(BT + (size_t)(col0 + r1) * KCAT + k0 + sc);
        short8 wb = *reinterpret_cast<const short8*>(BT + (size_t)(col0 + r2) * KCAT + k0 + sc);
        *reinterpret_cast<short8*>(&Bs[r1 * 40 + sc]) = wa;
        *reinterpret_cast<short8*>(&Bs[r2 * 40 + sc]) = wb;
        __syncthreads();

        short8 af[4], bfr[4];
        const int ka = (lane >> 4) * 8;
        #pragma unroll
        for (int i = 0; i < 4; ++i) {
            af[i]  = *reinterpret_cast<const short8*>(&As[(wr * 64 + i * 16 + (lane & 15)) * 40 + ka]);
            bfr[i] = *reinterpret_cast<const short8*>(&Bs[(wc * 64 + i * 16 + (lane & 15)) * 40 + ka]);
        }
        #pragma unroll
        for (int mi = 0; mi < 4; ++mi)
            #pragma unroll
            for (int ni = 0; ni < 4; ++ni)
                acc[mi][ni] = __builtin_amdgcn_mfma_f32_16x16x32_bf16(af[mi], bfr[ni], acc[mi][ni], 0, 0, 0);
        __syncthreads();
    }

    #pragma unroll
    for (int mi = 0; mi < 4; ++mi) {
        #pragma unroll
        for (int q = 0; q < 4; ++q) {
            int gm = row0 + wr * 64 + mi * 16 + (lane >> 4) * 4 + q;
            if (gm >= M) continue;
            #pragma unroll
            for (int ni = 0; ni < 4; ++ni) {
                int gn = col0 + wc * 64 + ni * 16 + (lane & 15);
                float v = acc[mi][ni][q] + bias[gn];
                if (RELU_BF16) {
                    v = fmaxf(v, 0.f);
                    ((unsigned short*)Cout)[(size_t)(mrow0 + gm) * NOUT + gn] = f2bf(v);
                } else {
                    ((float*)Cout)[(size_t)(mrow0 + gm) * NOUT + gn] = v;
                }
            }
        }
    }
}

// ================= launch =================
extern "C" void kernel_launch(void* const* d_in, const int* in_sizes, int n_in,
                              void* d_out, int out_size, void* d_ws, size_t ws_size,
                              hipStream_t stream) {
    const float* x     = (const float*)d_in[0];
    const float* W1    = (const float*)d_in[1];
    const float* root1 = (const float*)d_in[2];
    const float* b1    = (const float*)d_in[3];
    const float* W2    = (const float*)d_in[4];
    const float* root2 = (const float*)d_in[5];
    const float* b2    = (const float*)d_in[6];
    const int*   ei    = (const int*)d_in[7];
    const int*   et    = (const int*)d_in[8];
    const int* src = ei;
    const int* dst = ei + NE;
    float* out = (float*)d_out;

    char* ws = (char*)d_ws;
    int*            cnt    = (int*)(ws + 0);           // 640000
    int*            off    = (int*)(ws + 640000);      // 640000
    int*            cursor = (int*)(ws + 1280000);     // 640000
    int*            bsum   = (int*)(ws + 1920000);     // 2500 -> pad
    int*            ss     = (int*)(ws + 1923072);     // 2560000
    unsigned short* x_bf   = (unsigned short*)(ws + 4483072);   // 10,240,000
    unsigned short* h_bf   = (unsigned short*)(ws + 14723072);  // 10,240,000
    unsigned short* W1T    = (unsigned short*)(ws + 24963072);  // 1,179,648
    unsigned short* W2T    = (unsigned short*)(ws + 26142720);  // 589,824
    unsigned short* A      = (unsigned short*)(ws + 26732544);  // up to 92,160,000

    // chunk rows by available workspace for A
    size_t availA = (ws_size > 26732544) ? ws_size - 26732544 : 0;
    int rowsC = (int)((availA / ((size_t)KCAT * 2)));
    if (rowsC > NN) rowsC = NN;
    if (rowsC >= 256) rowsC &= ~127;
    if (rowsC < 1) rowsC = 1;   // degenerate; ws assumed >= ~30MB in practice

    const int NB = (NSEG + 255) / 256;

    // CSR
    hipMemsetAsync(cnt, 0, (size_t)NSEG * 4, stream);
    count_kernel<<<(NE + 255) / 256, 256, 0, stream>>>(dst, et, cnt);
    scan1<<<NB, 256, 0, stream>>>(cnt, off, bsum);
    scan2<<<1, 64, 0, stream>>>(bsum, NB);
    scan3<<<NB, 256, 0, stream>>>(off, bsum, cursor);
    bucket_kernel<<<(NE + 255) / 256, 256, 0, stream>>>(src, dst, et, cursor, ss);

    // weights + x conversion
    build_wt<<<(CH1 * KCAT + 255) / 256, 256, 0, stream>>>(root1, W1, W1T, CH1);
    build_wt<<<(CH2 * KCAT + 255) / 256, 256, 0, stream>>>(root2, W2, W2T, CH2);
    cvt_bf16<<<(NN * 256 / 4 + 255) / 256, 256, 0, stream>>>(x, x_bf, NN * 256 / 4);

    // layer 1: h_bf = relu(Acat(x) @ W1T^T + b1)  [bf16 out]
    for (int n0 = 0; n0 < NN; n0 += rowsC) {
        int rows = (NN - n0 < rowsC) ? (NN - n0) : rowsC;
        copy_rows<<<(rows * 64 + 255) / 256, 256, 0, stream>>>(x_bf, A, n0, rows);
        gather_all<<<(rows * NR + 3) / 4, 256, 0, stream>>>(x_bf, ss, off, cnt, A, n0, rows);
        dim3 g((rows + 127) / 128, CH1 / 128);
        gemm_mfma<CH1, true><<<g, 256, 0, stream>>>(A, W1T, b1, h_bf, rows, n0);
    }
    // layer 2: out = Acat(h) @ W2T^T + b2  [fp32 out]
    for (int n0 = 0; n0 < NN; n0 += rowsC) {
        int rows = (NN - n0 < rowsC) ? (NN - n0) : rowsC;
        copy_rows<<<(rows * 64 + 255) / 256, 256, 0, stream>>>(h_bf, A, n0, rows);
        gather_all<<<(rows * NR + 3) / 4, 256, 0, stream>>>(h_bf, ss, off, cnt, A, n0, rows);
        dim3 g((rows + 127) / 128, CH2 / 128);
        gemm_mfma<CH2, false><<<g, 256, 0, stream>>>(A, W2T, b2, out, rows, n0);
    }
}

// Round 6
// 541.237 us; speedup vs baseline: 10.3869x; 1.1647x over previous
//
#include <hip/hip_runtime.h>

#define NN 20000
#define NE 640000
#define NR 8
#define NSEG (NN * NR)
#define KCAT 2304            // 256 (root/self) + 8*256 (relations)
#define CH1 256
#define CH2 128

typedef __attribute__((ext_vector_type(8))) short short8;
typedef __attribute__((ext_vector_type(4))) float f32x4;

#define AS_GLOBAL __attribute__((address_space(1)))
#define AS_LDS    __attribute__((address_space(3)))

__device__ __forceinline__ float bf2f(unsigned short u) {
    unsigned int x = ((unsigned int)u) << 16;
    return __builtin_bit_cast(float, x);
}
__device__ __forceinline__ unsigned short f2bf(float f) {
    unsigned int u = __builtin_bit_cast(unsigned int, f);
    u = (u + 0x7FFFu + ((u >> 16) & 1u)) >> 16;   // RNE
    return (unsigned short)u;
}

// ================= CSR build =================
__global__ void count_kernel(const int* __restrict__ dst, const int* __restrict__ et,
                             int* __restrict__ cnt) {
    int e = blockIdx.x * blockDim.x + threadIdx.x;
    if (e < NE) atomicAdd(&cnt[et[e] * NN + dst[e]], 1);
}

__global__ void scan1(const int* __restrict__ cnt, int* __restrict__ off,
                      int* __restrict__ bsum) {
    __shared__ int s[256];
    int i = blockIdx.x * 256 + threadIdx.x;
    int v = (i < NSEG) ? cnt[i] : 0;
    s[threadIdx.x] = v;
    __syncthreads();
    for (int d = 1; d < 256; d <<= 1) {
        int t = (threadIdx.x >= d) ? s[threadIdx.x - d] : 0;
        __syncthreads();
        s[threadIdx.x] += t;
        __syncthreads();
    }
    if (i < NSEG) off[i] = s[threadIdx.x] - v;
    if (threadIdx.x == 255) bsum[blockIdx.x] = s[255];
}

// parallel single-block exclusive scan of nb (<=1024) block sums
__global__ __launch_bounds__(1024) void scan2(int* __restrict__ bsum, int nb) {
    __shared__ int s[1024];
    int t = threadIdx.x;
    int v = (t < nb) ? bsum[t] : 0;
    s[t] = v;
    __syncthreads();
    for (int d = 1; d < 1024; d <<= 1) {
        int tv = (t >= d) ? s[t - d] : 0;
        __syncthreads();
        s[t] += tv;
        __syncthreads();
    }
    if (t < nb) bsum[t] = s[t] - v;   // exclusive
}

__global__ void scan3(int* __restrict__ off, const int* __restrict__ bsum,
                      int* __restrict__ cursor) {
    int i = blockIdx.x * 256 + threadIdx.x;
    if (i < NSEG) {
        int o = off[i] + bsum[blockIdx.x];
        off[i] = o;
        cursor[i] = o;
    }
}

__global__ void bucket_kernel(const int* __restrict__ src, const int* __restrict__ dst,
                              const int* __restrict__ et, int* __restrict__ cursor,
                              int* __restrict__ ss) {
    int e = blockIdx.x * blockDim.x + threadIdx.x;
    if (e < NE) {
        int p = atomicAdd(&cursor[et[e] * NN + dst[e]], 1);
        ss[p] = src[e];
    }
}

// ================= conversions / packing =================
__global__ void cvt_bf16(const float* __restrict__ in, unsigned short* __restrict__ ob, int n4) {
    int i = blockIdx.x * blockDim.x + threadIdx.x;
    if (i < n4) {
        float4 v = reinterpret_cast<const float4*>(in)[i];
        ushort4 o;
        o.x = f2bf(v.x); o.y = f2bf(v.y); o.z = f2bf(v.z); o.w = f2bf(v.w);
        reinterpret_cast<ushort4*>(ob)[i] = o;
    }
}

// WT[n][k] over k<KCAT: k<256 -> root[k][n]; else W[r][kk][n]
__global__ void build_wt(const float* __restrict__ root, const float* __restrict__ W,
                         unsigned short* __restrict__ WT, int nout) {
    int i = blockIdx.x * 256 + threadIdx.x;
    if (i >= nout * KCAT) return;
    int n = i / KCAT, k = i - n * KCAT;
    float v;
    if (k < 256) v = root[(size_t)k * nout + n];
    else { int r = (k - 256) >> 8, kk = (k - 256) & 255; v = W[((size_t)r * 256 + kk) * nout + n]; }
    WT[(size_t)n * KCAT + k] = f2bf(v);
}

// fused: per node n, wave j==0 copies self row into A cols 0..255;
// waves j=1..8 compute segment mean for relation j-1 into cols 256+r*256
__global__ __launch_bounds__(256) void gather_all(const unsigned short* __restrict__ xb,
                                                  const int* __restrict__ ss,
                                                  const int* __restrict__ off,
                                                  const int* __restrict__ cnt,
                                                  unsigned short* __restrict__ A,
                                                  int n0, int rows) {
    int wid  = blockIdx.x * 4 + (threadIdx.x >> 6);
    int lane = threadIdx.x & 63;
    if (wid >= rows * (NR + 1)) return;
    int n = wid / (NR + 1);
    int j = wid - n * (NR + 1);
    if (j == 0) {   // self row copy
        reinterpret_cast<ushort4*>(A + (size_t)n * KCAT)[lane] =
            reinterpret_cast<const ushort4*>(xb + (size_t)(n0 + n) * 256)[lane];
        return;
    }
    int r    = j - 1;
    int idx  = r * NN + (n0 + n);
    int base = off[idx];
    int c    = cnt[idx];
    float a0 = 0.f, a1 = 0.f, a2 = 0.f, a3 = 0.f;
    for (int jj = 0; jj < c; ++jj) {
        int s = ss[base + jj];
        ushort4 v = reinterpret_cast<const ushort4*>(xb + (size_t)s * 256)[lane];
        a0 += bf2f(v.x); a1 += bf2f(v.y); a2 += bf2f(v.z); a3 += bf2f(v.w);
    }
    float inv = (c > 0) ? 1.f / (float)c : 0.f;
    ushort4 o;
    o.x = f2bf(a0 * inv); o.y = f2bf(a1 * inv); o.z = f2bf(a2 * inv); o.w = f2bf(a3 * inv);
    reinterpret_cast<ushort4*>(A + (size_t)n * KCAT + 256 + r * 256)[lane] = o;
}

// ================= MFMA GEMM =================
// C[M x NOUT] = A[M x KCAT](bf16) @ BT[NOUT x KCAT]^T(bf16) + bias.
// Staging: global_load_lds width=16, linear LDS [128][32] shorts (m97 structure).
template<int NOUT, bool RELU_BF16>
__global__ __launch_bounds__(256) void gemm_mfma(const unsigned short* __restrict__ A,
                                                 const unsigned short* __restrict__ BT,
                                                 const float* __restrict__ bias,
                                                 void* __restrict__ Cout,
                                                 int M, int mrow0) {
    __shared__ __align__(16) unsigned short As[128 * 32];
    __shared__ __align__(16) unsigned short Bs[128 * 32];
    const int tid  = threadIdx.x;
    const int lane = tid & 63;
    const int w    = tid >> 6;
    const int wr   = w >> 1, wc = w & 1;
    const int row0 = blockIdx.x * 128;
    const int col0 = blockIdx.y * 128;

    // staging geometry: instr i covers rows i*64 + w*16 + (lane>>2), k shorts (lane&3)*8
    const int srow = lane >> 2;
    const int skk  = (lane & 3) * 8;
    int ra0 = row0 + w * 16 + srow;
    int ra1 = row0 + 64 + w * 16 + srow;
    ra0 = (ra0 < M) ? ra0 : (M - 1);     // clamp OOB rows (garbage never stored)
    ra1 = (ra1 < M) ? ra1 : (M - 1);
    const unsigned short* pa0 = A + (size_t)ra0 * KCAT + skk;
    const unsigned short* pa1 = A + (size_t)ra1 * KCAT + skk;
    const unsigned short* pb0 = BT + (size_t)(col0 + w * 16 + srow) * KCAT + skk;
    const unsigned short* pb1 = BT + (size_t)(col0 + 64 + w * 16 + srow) * KCAT + skk;
    unsigned short* lA0 = As + w * 512;          // wave-uniform LDS bases
    unsigned short* lA1 = As + 2048 + w * 512;
    unsigned short* lB0 = Bs + w * 512;
    unsigned short* lB1 = Bs + 2048 + w * 512;

    f32x4 acc[4][4] = {};
    const int fr = lane & 15;
    const int ka = (lane >> 4) * 8;

    for (int k0 = 0; k0 < KCAT; k0 += 32) {
        __builtin_amdgcn_global_load_lds((const AS_GLOBAL unsigned int*)(pa0 + k0),
                                         (AS_LDS unsigned int*)lA0, 16, 0, 0);
        __builtin_amdgcn_global_load_lds((const AS_GLOBAL unsigned int*)(pa1 + k0),
                                         (AS_LDS unsigned int*)lA1, 16, 0, 0);
        __builtin_amdgcn_global_load_lds((const AS_GLOBAL unsigned int*)(pb0 + k0),
                                         (AS_LDS unsigned int*)lB0, 16, 0, 0);
        __builtin_amdgcn_global_load_lds((const AS_GLOBAL unsigned int*)(pb1 + k0),
                                         (AS_LDS unsigned int*)lB1, 16, 0, 0);
        __syncthreads();

        short8 af[4], bfrag[4];
        #pragma unroll
        for (int i = 0; i < 4; ++i) {
            af[i]    = *reinterpret_cast<const short8*>(&As[(wr * 64 + i * 16 + fr) * 32 + ka]);
            bfrag[i] = *reinterpret_cast<const short8*>(&Bs[(wc * 64 + i * 16 + fr) * 32 + ka]);
        }
        #pragma unroll
        for (int mi = 0; mi < 4; ++mi)
            #pragma unroll
            for (int ni = 0; ni < 4; ++ni)
                acc[mi][ni] = __builtin_amdgcn_mfma_f32_16x16x32_bf16(af[mi], bfrag[ni], acc[mi][ni], 0, 0, 0);
        __syncthreads();
    }

    #pragma unroll
    for (int mi = 0; mi < 4; ++mi) {
        #pragma unroll
        for (int q = 0; q < 4; ++q) {
            int gm = row0 + wr * 64 + mi * 16 + (lane >> 4) * 4 + q;
            if (gm >= M) continue;
            #pragma unroll
            for (int ni = 0; ni < 4; ++ni) {
                int gn = col0 + wc * 64 + ni * 16 + fr;
                float v = acc[mi][ni][q] + bias[gn];
                if (RELU_BF16) {
                    v = fmaxf(v, 0.f);
                    ((unsigned short*)Cout)[(size_t)(mrow0 + gm) * NOUT + gn] = f2bf(v);
                } else {
                    ((float*)Cout)[(size_t)(mrow0 + gm) * NOUT + gn] = v;
                }
            }
        }
    }
}

// ================= launch =================
extern "C" void kernel_launch(void* const* d_in, const int* in_sizes, int n_in,
                              void* d_out, int out_size, void* d_ws, size_t ws_size,
                              hipStream_t stream) {
    const float* x     = (const float*)d_in[0];
    const float* W1    = (const float*)d_in[1];
    const float* root1 = (const float*)d_in[2];
    const float* b1    = (const float*)d_in[3];
    const float* W2    = (const float*)d_in[4];
    const float* root2 = (const float*)d_in[5];
    const float* b2    = (const float*)d_in[6];
    const int*   ei    = (const int*)d_in[7];
    const int*   et    = (const int*)d_in[8];
    const int* src = ei;
    const int* dst = ei + NE;
    float* out = (float*)d_out;

    char* ws = (char*)d_ws;
    int*            cnt    = (int*)(ws + 0);           // 640000
    int*            off    = (int*)(ws + 640000);      // 640000
    int*            cursor = (int*)(ws + 1280000);     // 640000
    int*            bsum   = (int*)(ws + 1920000);     // 2500 -> pad
    int*            ss     = (int*)(ws + 1923072);     // 2560000
    unsigned short* x_bf   = (unsigned short*)(ws + 4483072);   // 10,240,000
    unsigned short* h_bf   = (unsigned short*)(ws + 14723072);  // 10,240,000
    unsigned short* W1T    = (unsigned short*)(ws + 24963072);  // 1,179,648
    unsigned short* W2T    = (unsigned short*)(ws + 26142720);  // 589,824
    unsigned short* A      = (unsigned short*)(ws + 26732544);  // up to 92,160,000

    // chunk rows by available workspace for A
    size_t availA = (ws_size > 26732544) ? ws_size - 26732544 : 0;
    int rowsC = (int)((availA / ((size_t)KCAT * 2)));
    if (rowsC > NN) rowsC = NN;
    if (rowsC >= 256) rowsC &= ~127;
    if (rowsC < 1) rowsC = 1;

    const int NB = (NSEG + 255) / 256;   // 625

    // CSR
    hipMemsetAsync(cnt, 0, (size_t)NSEG * 4, stream);
    count_kernel<<<(NE + 255) / 256, 256, 0, stream>>>(dst, et, cnt);
    scan1<<<NB, 256, 0, stream>>>(cnt, off, bsum);
    scan2<<<1, 1024, 0, stream>>>(bsum, NB);
    scan3<<<NB, 256, 0, stream>>>(off, bsum, cursor);
    bucket_kernel<<<(NE + 255) / 256, 256, 0, stream>>>(src, dst, et, cursor, ss);

    // weights + x conversion
    build_wt<<<(CH1 * KCAT + 255) / 256, 256, 0, stream>>>(root1, W1, W1T, CH1);
    build_wt<<<(CH2 * KCAT + 255) / 256, 256, 0, stream>>>(root2, W2, W2T, CH2);
    cvt_bf16<<<(NN * 256 / 4 + 255) / 256, 256, 0, stream>>>(x, x_bf, NN * 256 / 4);

    // layer 1: h_bf = relu(Acat(x) @ W1T^T + b1)  [bf16 out]
    for (int n0 = 0; n0 < NN; n0 += rowsC) {
        int rows = (NN - n0 < rowsC) ? (NN - n0) : rowsC;
        gather_all<<<(rows * (NR + 1) + 3) / 4, 256, 0, stream>>>(x_bf, ss, off, cnt, A, n0, rows);
        dim3 g((rows + 127) / 128, CH1 / 128);
        gemm_mfma<CH1, true><<<g, 256, 0, stream>>>(A, W1T, b1, h_bf, rows, n0);
    }
    // layer 2: out = Acat(h) @ W2T^T + b2  [fp32 out]
    for (int n0 = 0; n0 < NN; n0 += rowsC) {
        int rows = (NN - n0 < rowsC) ? (NN - n0) : rowsC;
        gather_all<<<(rows * (NR + 1) + 3) / 4, 256, 0, stream>>>(h_bf, ss, off, cnt, A, n0, rows);
        dim3 g((rows + 127) / 128, CH2 / 128);
        gemm_mfma<CH2, false><<<g, 256, 0, stream>>>(A, W2T, b2, out, rows, n0);
    }
}

// Round 7
// 452.963 us; speedup vs baseline: 12.4111x; 1.1949x over previous
//
#include <hip/hip_runtime.h>

#define NN 20000
#define NE 640000
#define NR 8
#define NSEG (NN * NR)
#define KCAT 2304            // 256 (root/self) + 8*256 (relations)
#define CH1 256
#define CH2 128

typedef __attribute__((ext_vector_type(8))) short short8;
typedef __attribute__((ext_vector_type(4))) float f32x4;

#define AS_GLOBAL __attribute__((address_space(1)))
#define AS_LDS    __attribute__((address_space(3)))

__device__ __forceinline__ float bf2f(unsigned short u) {
    unsigned int x = ((unsigned int)u) << 16;
    return __builtin_bit_cast(float, x);
}
__device__ __forceinline__ unsigned short f2bf(float f) {
    unsigned int u = __builtin_bit_cast(unsigned int, f);
    u = (u + 0x7FFFu + ((u >> 16) & 1u)) >> 16;   // RNE
    return (unsigned short)u;
}
__device__ __forceinline__ f32x4 cvt4(ushort4 v) {
    f32x4 r;
    r.x = bf2f(v.x); r.y = bf2f(v.y); r.z = bf2f(v.z); r.w = bf2f(v.w);
    return r;
}

// ================= CSR build =================
__global__ void count_kernel(const int* __restrict__ dst, const int* __restrict__ et,
                             int* __restrict__ cnt) {
    int e = blockIdx.x * blockDim.x + threadIdx.x;
    if (e < NE) atomicAdd(&cnt[et[e] * NN + dst[e]], 1);
}

__global__ void scan1(const int* __restrict__ cnt, int* __restrict__ off,
                      int* __restrict__ bsum) {
    __shared__ int s[256];
    int i = blockIdx.x * 256 + threadIdx.x;
    int v = (i < NSEG) ? cnt[i] : 0;
    s[threadIdx.x] = v;
    __syncthreads();
    for (int d = 1; d < 256; d <<= 1) {
        int t = (threadIdx.x >= d) ? s[threadIdx.x - d] : 0;
        __syncthreads();
        s[threadIdx.x] += t;
        __syncthreads();
    }
    if (i < NSEG) off[i] = s[threadIdx.x] - v;
    if (threadIdx.x == 255) bsum[blockIdx.x] = s[255];
}

// parallel single-block exclusive scan of nb (<=1024) block sums
__global__ __launch_bounds__(1024) void scan2(int* __restrict__ bsum, int nb) {
    __shared__ int s[1024];
    int t = threadIdx.x;
    int v = (t < nb) ? bsum[t] : 0;
    s[t] = v;
    __syncthreads();
    for (int d = 1; d < 1024; d <<= 1) {
        int tv = (t >= d) ? s[t - d] : 0;
        __syncthreads();
        s[t] += tv;
        __syncthreads();
    }
    if (t < nb) bsum[t] = s[t] - v;   // exclusive
}

__global__ void scan3(int* __restrict__ off, const int* __restrict__ bsum,
                      int* __restrict__ cursor) {
    int i = blockIdx.x * 256 + threadIdx.x;
    if (i < NSEG) {
        int o = off[i] + bsum[blockIdx.x];
        off[i] = o;
        cursor[i] = o;
    }
}

__global__ void bucket_kernel(const int* __restrict__ src, const int* __restrict__ dst,
                              const int* __restrict__ et, int* __restrict__ cursor,
                              int* __restrict__ ss) {
    int e = blockIdx.x * blockDim.x + threadIdx.x;
    if (e < NE) {
        int p = atomicAdd(&cursor[et[e] * NN + dst[e]], 1);
        ss[p] = src[e];
    }
}

// ================= conversions / packing =================
__global__ void cvt_bf16(const float* __restrict__ in, unsigned short* __restrict__ ob, int n4) {
    int i = blockIdx.x * blockDim.x + threadIdx.x;
    if (i < n4) {
        float4 v = reinterpret_cast<const float4*>(in)[i];
        ushort4 o;
        o.x = f2bf(v.x); o.y = f2bf(v.y); o.z = f2bf(v.z); o.w = f2bf(v.w);
        reinterpret_cast<ushort4*>(ob)[i] = o;
    }
}

// WT[n][k] over k<KCAT: k<256 -> root[k][n]; else W[r][kk][n]
__global__ void build_wt(const float* __restrict__ root, const float* __restrict__ W,
                         unsigned short* __restrict__ WT, int nout) {
    int i = blockIdx.x * 256 + threadIdx.x;
    if (i >= nout * KCAT) return;
    int n = i / KCAT, k = i - n * KCAT;
    float v;
    if (k < 256) v = root[(size_t)k * nout + n];
    else { int r = (k - 256) >> 8, kk = (k - 256) & 255; v = W[((size_t)r * 256 + kk) * nout + n]; }
    WT[(size_t)n * KCAT + k] = f2bf(v);
}

// fused: per node n, wave j==0 copies self row into A cols 0..255;
// waves j=1..8 compute segment mean for relation j-1 into cols 256+r*256.
// Unroll-4 with independent accumulators: 4 row-gathers in flight per wave.
__global__ __launch_bounds__(256) void gather_all(const unsigned short* __restrict__ xb,
                                                  const int* __restrict__ ss,
                                                  const int* __restrict__ off,
                                                  const int* __restrict__ cnt,
                                                  unsigned short* __restrict__ A,
                                                  int n0, int rows) {
    int wid  = blockIdx.x * 4 + (threadIdx.x >> 6);
    int lane = threadIdx.x & 63;
    if (wid >= rows * (NR + 1)) return;
    int n = wid / (NR + 1);
    int j = wid - n * (NR + 1);
    if (j == 0) {   // self row copy
        reinterpret_cast<ushort4*>(A + (size_t)n * KCAT)[lane] =
            reinterpret_cast<const ushort4*>(xb + (size_t)(n0 + n) * 256)[lane];
        return;
    }
    int r    = j - 1;
    int idx  = r * NN + (n0 + n);
    int base = off[idx];
    int c    = cnt[idx];

    f32x4 a0 = {0.f, 0.f, 0.f, 0.f}, a1 = a0, a2 = a0, a3 = a0;
    int jj = 0;
    for (; jj + 4 <= c; jj += 4) {
        int s0 = ss[base + jj + 0];
        int s1 = ss[base + jj + 1];
        int s2 = ss[base + jj + 2];
        int s3 = ss[base + jj + 3];
        ushort4 v0 = reinterpret_cast<const ushort4*>(xb + (size_t)s0 * 256)[lane];
        ushort4 v1 = reinterpret_cast<const ushort4*>(xb + (size_t)s1 * 256)[lane];
        ushort4 v2 = reinterpret_cast<const ushort4*>(xb + (size_t)s2 * 256)[lane];
        ushort4 v3 = reinterpret_cast<const ushort4*>(xb + (size_t)s3 * 256)[lane];
        a0 += cvt4(v0); a1 += cvt4(v1); a2 += cvt4(v2); a3 += cvt4(v3);
    }
    int rem = c - jj;   // 0..3, wave-uniform
    if (rem > 0) {      // issue remaining loads together, then accumulate
        int s0 = ss[base + jj + 0];
        int s1 = (rem > 1) ? ss[base + jj + 1] : s0;
        int s2 = (rem > 2) ? ss[base + jj + 2] : s0;
        ushort4 v0 = reinterpret_cast<const ushort4*>(xb + (size_t)s0 * 256)[lane];
        ushort4 v1 = (rem > 1) ? reinterpret_cast<const ushort4*>(xb + (size_t)s1 * 256)[lane] : make_ushort4(0,0,0,0);
        ushort4 v2 = (rem > 2) ? reinterpret_cast<const ushort4*>(xb + (size_t)s2 * 256)[lane] : make_ushort4(0,0,0,0);
        a0 += cvt4(v0);
        if (rem > 1) a1 += cvt4(v1);
        if (rem > 2) a2 += cvt4(v2);
    }
    f32x4 acc = (a0 + a1) + (a2 + a3);
    float inv = (c > 0) ? 1.f / (float)c : 0.f;
    ushort4 o;
    o.x = f2bf(acc.x * inv); o.y = f2bf(acc.y * inv);
    o.z = f2bf(acc.z * inv); o.w = f2bf(acc.w * inv);
    reinterpret_cast<ushort4*>(A + (size_t)n * KCAT + 256 + r * 256)[lane] = o;
}

// ================= MFMA GEMM =================
// C[M x NOUT] = A[M x KCAT](bf16) @ BT[NOUT x KCAT]^T(bf16) + bias.
// Staging: global_load_lds width=16, linear LDS (m97 structure).
// BN: column-tile (128 -> wave tile 64x64; 64 -> wave tile 32x64).
template<int NOUT, int BN, bool RELU_BF16>
__global__ __launch_bounds__(256) void gemm_mfma(const unsigned short* __restrict__ A,
                                                 const unsigned short* __restrict__ BT,
                                                 const float* __restrict__ bias,
                                                 void* __restrict__ Cout,
                                                 int M, int mrow0) {
    constexpr int MI = (BN == 128) ? 4 : 2;     // 16-row fragments per wave
    __shared__ __align__(16) unsigned short As[128 * 32];
    __shared__ __align__(16) unsigned short Bs[BN * 32];
    const int tid  = threadIdx.x;
    const int lane = tid & 63;
    const int w    = tid >> 6;
    const int wr   = (BN == 128) ? (w >> 1) : w;
    const int wc   = (BN == 128) ? (w & 1) : 0;
    const int wrow = wr * (MI * 16);
    const int wcol = wc * 64;
    const int row0 = blockIdx.x * 128;
    const int col0 = blockIdx.y * BN;

    // staging geometry: instr covers 16 rows x 32 shorts per wave
    const int srow = lane >> 2;
    const int skk  = (lane & 3) * 8;
    int ra0 = row0 + w * 16 + srow;
    int ra1 = row0 + 64 + w * 16 + srow;
    ra0 = (ra0 < M) ? ra0 : (M - 1);     // clamp OOB rows (garbage never stored)
    ra1 = (ra1 < M) ? ra1 : (M - 1);
    const unsigned short* pa0 = A + (size_t)ra0 * KCAT + skk;
    const unsigned short* pa1 = A + (size_t)ra1 * KCAT + skk;
    const unsigned short* pb0 = BT + (size_t)(col0 + w * 16 + srow) * KCAT + skk;
    const unsigned short* pb1 = BT + (size_t)(col0 + 64 + w * 16 + srow) * KCAT + skk; // BN==128 only
    unsigned short* lA0 = As + w * 512;
    unsigned short* lA1 = As + 2048 + w * 512;
    unsigned short* lB0 = Bs + w * 512;
    unsigned short* lB1 = Bs + 2048 + w * 512;

    f32x4 acc[MI][4] = {};
    const int fr = lane & 15;
    const int ka = (lane >> 4) * 8;

    for (int k0 = 0; k0 < KCAT; k0 += 32) {
        __builtin_amdgcn_global_load_lds((const AS_GLOBAL unsigned int*)(pa0 + k0),
                                         (AS_LDS unsigned int*)lA0, 16, 0, 0);
        __builtin_amdgcn_global_load_lds((const AS_GLOBAL unsigned int*)(pa1 + k0),
                                         (AS_LDS unsigned int*)lA1, 16, 0, 0);
        __builtin_amdgcn_global_load_lds((const AS_GLOBAL unsigned int*)(pb0 + k0),
                                         (AS_LDS unsigned int*)lB0, 16, 0, 0);
        if (BN == 128)
            __builtin_amdgcn_global_load_lds((const AS_GLOBAL unsigned int*)(pb1 + k0),
                                             (AS_LDS unsigned int*)lB1, 16, 0, 0);
        __syncthreads();

        short8 af[MI], bfrag[4];
        #pragma unroll
        for (int i = 0; i < MI; ++i)
            af[i] = *reinterpret_cast<const short8*>(&As[(wrow + i * 16 + fr) * 32 + ka]);
        #pragma unroll
        for (int i = 0; i < 4; ++i)
            bfrag[i] = *reinterpret_cast<const short8*>(&Bs[(wcol + i * 16 + fr) * 32 + ka]);
        #pragma unroll
        for (int mi = 0; mi < MI; ++mi)
            #pragma unroll
            for (int ni = 0; ni < 4; ++ni)
                acc[mi][ni] = __builtin_amdgcn_mfma_f32_16x16x32_bf16(af[mi], bfrag[ni], acc[mi][ni], 0, 0, 0);
        __syncthreads();
    }

    #pragma unroll
    for (int mi = 0; mi < MI; ++mi) {
        #pragma unroll
        for (int q = 0; q < 4; ++q) {
            int gm = row0 + wrow + mi * 16 + (lane >> 4) * 4 + q;
            if (gm >= M) continue;
            #pragma unroll
            for (int ni = 0; ni < 4; ++ni) {
                int gn = col0 + wcol + ni * 16 + fr;
                float v = acc[mi][ni][q] + bias[gn];
                if (RELU_BF16) {
                    v = fmaxf(v, 0.f);
                    ((unsigned short*)Cout)[(size_t)(mrow0 + gm) * NOUT + gn] = f2bf(v);
                } else {
                    ((float*)Cout)[(size_t)(mrow0 + gm) * NOUT + gn] = v;
                }
            }
        }
    }
}

// ================= launch =================
extern "C" void kernel_launch(void* const* d_in, const int* in_sizes, int n_in,
                              void* d_out, int out_size, void* d_ws, size_t ws_size,
                              hipStream_t stream) {
    const float* x     = (const float*)d_in[0];
    const float* W1    = (const float*)d_in[1];
    const float* root1 = (const float*)d_in[2];
    const float* b1    = (const float*)d_in[3];
    const float* W2    = (const float*)d_in[4];
    const float* root2 = (const float*)d_in[5];
    const float* b2    = (const float*)d_in[6];
    const int*   ei    = (const int*)d_in[7];
    const int*   et    = (const int*)d_in[8];
    const int* src = ei;
    const int* dst = ei + NE;
    float* out = (float*)d_out;

    char* ws = (char*)d_ws;
    int*            cnt    = (int*)(ws + 0);           // 640000
    int*            off    = (int*)(ws + 640000);      // 640000
    int*            cursor = (int*)(ws + 1280000);     // 640000
    int*            bsum   = (int*)(ws + 1920000);     // 2500 -> pad
    int*            ss     = (int*)(ws + 1923072);     // 2560000
    unsigned short* x_bf   = (unsigned short*)(ws + 4483072);   // 10,240,000
    unsigned short* h_bf   = (unsigned short*)(ws + 14723072);  // 10,240,000
    unsigned short* W1T    = (unsigned short*)(ws + 24963072);  // 1,179,648
    unsigned short* W2T    = (unsigned short*)(ws + 26142720);  // 589,824
    unsigned short* A      = (unsigned short*)(ws + 26732544);  // up to 92,160,000

    // chunk rows by available workspace for A
    size_t availA = (ws_size > 26732544) ? ws_size - 26732544 : 0;
    int rowsC = (int)((availA / ((size_t)KCAT * 2)));
    if (rowsC > NN) rowsC = NN;
    if (rowsC >= 256) rowsC &= ~127;
    if (rowsC < 1) rowsC = 1;

    const int NB = (NSEG + 255) / 256;   // 625

    // CSR
    hipMemsetAsync(cnt, 0, (size_t)NSEG * 4, stream);
    count_kernel<<<(NE + 255) / 256, 256, 0, stream>>>(dst, et, cnt);
    scan1<<<NB, 256, 0, stream>>>(cnt, off, bsum);
    scan2<<<1, 1024, 0, stream>>>(bsum, NB);
    scan3<<<NB, 256, 0, stream>>>(off, bsum, cursor);
    bucket_kernel<<<(NE + 255) / 256, 256, 0, stream>>>(src, dst, et, cursor, ss);

    // weights + x conversion
    build_wt<<<(CH1 * KCAT + 255) / 256, 256, 0, stream>>>(root1, W1, W1T, CH1);
    build_wt<<<(CH2 * KCAT + 255) / 256, 256, 0, stream>>>(root2, W2, W2T, CH2);
    cvt_bf16<<<(NN * 256 / 4 + 255) / 256, 256, 0, stream>>>(x, x_bf, NN * 256 / 4);

    // layer 1: h_bf = relu(Acat(x) @ W1T^T + b1)  [bf16 out]
    for (int n0 = 0; n0 < NN; n0 += rowsC) {
        int rows = (NN - n0 < rowsC) ? (NN - n0) : rowsC;
        gather_all<<<(rows * (NR + 1) + 3) / 4, 256, 0, stream>>>(x_bf, ss, off, cnt, A, n0, rows);
        dim3 g((rows + 127) / 128, CH1 / 128);
        gemm_mfma<CH1, 128, true><<<g, 256, 0, stream>>>(A, W1T, b1, h_bf, rows, n0);
    }
    // layer 2: out = Acat(h) @ W2T^T + b2  [fp32 out], BN=64 fills the GPU
    for (int n0 = 0; n0 < NN; n0 += rowsC) {
        int rows = (NN - n0 < rowsC) ? (NN - n0) : rowsC;
        gather_all<<<(rows * (NR + 1) + 3) / 4, 256, 0, stream>>>(h_bf, ss, off, cnt, A, n0, rows);
        dim3 g((rows + 127) / 128, CH2 / 64);
        gemm_mfma<CH2, 64, false><<<g, 256, 0, stream>>>(A, W2T, b2, out, rows, n0);
    }
}